// Round 2
// baseline (307.334 us; speedup 1.0000x reference)
//
#include <hip/hip_runtime.h>

// Mutual_Information_Loss: inputs [8,64,256,256] f32 x2, output scalar f32.
//
// Math collapse (verified passing, absmax 0.0): after L2-normalize over C,
// the only integer-bin hits are exact +-0.0 inputs (bin 0). So the whole
// 268 MB problem reduces to "find the exact-zero positions", then a tiny
// closed-form entropy/joint/smooth-L1 evaluation over [256 x 256].
//
// R2 change: atomics/branches inside the streaming loop were scheduling
// poison (compiler would not hoist loads across the atomic cluster ->
// ~1 outstanding load/wave, 2.85 TB/s; R1's batch-predicate made it drain
// vmcnt(0) per batch, worse). Now the hot loop is side-effect-free: each
// thread builds a 64-bit zero-position bitmask per tensor (branchless,
// static bit indices), letting the compiler software-pipeline all 16
// iterations' loads. Atomics run in a cold epilogue (~8 threads grid-wide).

static constexpr int WH     = 65536;               // 256*256 spatial positions
static constexpr int NELEM  = 8 * 64 * 256 * 256;  // 33554432 per tensor
static constexpr int N4     = NELEM / 4;           // 8388608 float4 per tensor
static constexpr int GRID   = 2048;
static constexpr int BLOCK  = 256;
static constexpr int STRIDE = GRID * BLOCK;        // 524288 float4
static constexpr int ITERS  = N4 / STRIDE;         // 16 (exact, no remainder)

// ---------------------------------------------------------------- kernel 1 --
// Zero scan. flat = ((b*64+c)*256+w)*256+h, so (w*256+h) = flat & 65535.
// Grid-stride layout (R0-proven shape): thread idx handles float4 indices
// idx + k*STRIDE, k = 0..15. Bit (k*4+c) of the mask marks a zero at
// component c of iteration k.
__global__ __launch_bounds__(256) void count_zeros_kernel(
    const float4* __restrict__ a, const float4* __restrict__ b,
    unsigned int* __restrict__ za, unsigned int* __restrict__ zb) {
    int idx = blockIdx.x * BLOCK + threadIdx.x;
    unsigned long long ma = 0ull;
    unsigned long long mb = 0ull;
#pragma unroll
    for (int k = 0; k < ITERS; ++k) {
        float4 va = a[idx + k * STRIDE];
        float4 vb = b[idx + k * STRIDE];
        unsigned long long ha = (va.x == 0.0f ? 1ull : 0ull)
                              | (va.y == 0.0f ? 2ull : 0ull)
                              | (va.z == 0.0f ? 4ull : 0ull)
                              | (va.w == 0.0f ? 8ull : 0ull);
        unsigned long long hb = (vb.x == 0.0f ? 1ull : 0ull)
                              | (vb.y == 0.0f ? 2ull : 0ull)
                              | (vb.z == 0.0f ? 4ull : 0ull)
                              | (vb.w == 0.0f ? 8ull : 0ull);
        ma |= ha << (k * 4);   // static shift amounts after unroll
        mb |= hb << (k * 4);
    }
    // cold epilogue: zeros are ~4 per tensor, so this runs on ~8 threads
    // in the entire grid. Atomics + loops here cannot hurt the hot loop.
    if (__builtin_expect(ma != 0ull, 0)) {
        while (ma) {
            int bit = __builtin_ctzll(ma);
            ma &= ma - 1;
            int k = bit >> 2, c = bit & 3;
            unsigned e = (((unsigned)(idx + k * STRIDE)) * 4u + (unsigned)c)
                         & (unsigned)(WH - 1);
            atomicAdd(&za[e], 1u);
        }
    }
    if (__builtin_expect(mb != 0ull, 0)) {
        while (mb) {
            int bit = __builtin_ctzll(mb);
            mb &= mb - 1;
            int k = bit >> 2, c = bit & 3;
            unsigned e = (((unsigned)(idx + k * STRIDE)) * 4u + (unsigned)c)
                         & (unsigned)(WH - 1);
            atomicAdd(&zb[e], 1u);
        }
    }
}

// ---------------------------------------------------------------- kernel 2 --
// One block per w (256 blocks), one thread per j (256 threads).
// Step 1: block-reduce the two row entropies e_fo[w], e_f5[w].
// Step 2: thread j loops i=0..255 computing the joint-entropy column sum,
//         then the smooth-L1 element; block-reduce -> partial[w].
__global__ void joint_loss_kernel(const unsigned int* __restrict__ za,
                                  const unsigned int* __restrict__ zb,
                                  float* __restrict__ partial) {
    __shared__ float redA[256];
    __shared__ float redB[256];
    int w = blockIdx.x;
    int t = threadIdx.x;

    // entropy terms: h = t
    float qa = (float)za[w * 256 + t] * (1.0f / 65536.0f);
    float qb = (float)zb[w * 256 + t] * (1.0f / 65536.0f);
    redA[t] = qa * logf(qa + 1e-8f);   // 0 when qa==0 (0 * finite)
    redB[t] = qb * logf(qb + 1e-8f);
    __syncthreads();
    for (int s = 128; s > 0; s >>= 1) {
        if (t < s) {
            redA[t] += redA[t + s];
            redB[t] += redB[t + s];
        }
        __syncthreads();
    }
    float ea = -redA[0];   // e_fo[w]
    float eb = -redB[0];   // e_f5[w]
    __syncthreads();

    // which bin does each row-entropy value match? (reference: x == i test)
    int ia = (ea == floorf(ea) && ea >= 0.0f && ea <= 255.0f) ? (int)ea : -1;
    int ib = (eb == floorf(eb) && eb >= 0.0f && eb <= 255.0f) ? (int)eb : -1;

    int j = t;
    float p0 = (j == ib) ? 1.0f : 0.0f;  // c=0 channel of x_p at bin j
    float sum_i = 0.0f;
    for (int i = 0; i < 256; ++i) {
        float m0   = (i == ia) ? 1.0f : 0.0f;             // c=0 of x_ms
        float base = ((i == 0) == (j == 0)) ? 255.0f : 0.0f;  // 255 c>=1 chans
        float c0   = m0 * p0 + (1.0f - m0) * (1.0f - p0);
        float s    = base + c0;
        float pm   = s * (1.0f / 65536.0f);
        sum_i += pm * logf(pm + 1e-8f);   // pm==0 -> exact 0 contribution
    }
    float J = -256.0f * sum_i;
    float S = (j == 0) ? (ea + eb) : 0.0f;
    float d = S - J;
    float ad = fabsf(d);
    float loss = (ad < 1.0f) ? 0.5f * d * d : ad - 0.5f;

    redA[t] = loss;
    __syncthreads();
    for (int s = 128; s > 0; s >>= 1) {
        if (t < s) redA[t] += redA[t + s];
        __syncthreads();
    }
    if (t == 0) partial[w] = redA[0];
}

// ---------------------------------------------------------------- kernel 3 --
__global__ void final_reduce_kernel(const float* __restrict__ partial,
                                    float* __restrict__ out) {
    __shared__ float red[256];
    int t = threadIdx.x;
    red[t] = partial[t];
    __syncthreads();
    for (int s = 128; s > 0; s >>= 1) {
        if (t < s) red[t] += red[t + s];
        __syncthreads();
    }
    if (t == 0) out[0] = red[0] * (1.0f / 65536.0f);
}

extern "C" void kernel_launch(void* const* d_in, const int* in_sizes, int n_in,
                              void* d_out, int out_size, void* d_ws, size_t ws_size,
                              hipStream_t stream) {
    const float* fo = (const float*)d_in[0];
    const float* f5 = (const float*)d_in[1];
    float* out = (float*)d_out;

    unsigned int* za = (unsigned int*)d_ws;
    unsigned int* zb = za + WH;
    float* partial   = (float*)(zb + WH);

    // zero the counters (ws is poisoned 0xAA before every launch)
    hipMemsetAsync(d_ws, 0, 2 * WH * sizeof(unsigned int), stream);

    count_zeros_kernel<<<GRID, BLOCK, 0, stream>>>(
        (const float4*)fo, (const float4*)f5, za, zb);
    joint_loss_kernel<<<256, 256, 0, stream>>>(za, zb, partial);
    final_reduce_kernel<<<1, 256, 0, stream>>>(partial, out);
}

// Round 4
// 266.455 us; speedup vs baseline: 1.1534x; 1.1534x over previous
//
#include <hip/hip_runtime.h>

// Mutual_Information_Loss: inputs [8,64,256,256] f32 x2, output scalar f32.
//
// Math collapse (verified passing, absmax 0.0): after L2-normalize over C,
// the only integer-bin hits are exact +-0.0 inputs (bin 0). So the whole
// 268 MB problem reduces to "find the exact-zero positions", then a tiny
// closed-form entropy/joint/smooth-L1 evaluation over [256 x 256].
//
// R4 = R3 with the compile fix: __builtin_nontemporal_load needs a native
// clang vector type, not HIP's uint4 class -> use ext_vector_type(4).
//
// Theory (R3): R0->R2 showed more per-wave MLP monotonically HURTS
// (94->115us) at constant FETCH_SIZE == exactly one tensor. Diagnosis:
// 268 MB working set vs 256 MB LLC = pathological thrash; every miss
// allocates + evicts a line the other stream was about to hit, and fill
// traffic competes with demand. Fix: NON-TEMPORAL loads so stream-once
// data never allocates -> pure HBM streaming path. Lockstep grid-stride
// window, side-effect-free bitmask hot loop, cold epilogue atomics.

typedef unsigned int uint4v __attribute__((ext_vector_type(4)));

static constexpr int WH     = 65536;               // 256*256 spatial positions
static constexpr int NELEM  = 8 * 64 * 256 * 256;  // 33554432 per tensor
static constexpr int N4     = NELEM / 4;           // 8388608 float4 per tensor
static constexpr int GRID   = 2048;
static constexpr int BLOCK  = 256;
static constexpr int STRIDE = GRID * BLOCK;        // 524288 float4
static constexpr int ITERS  = N4 / STRIDE;         // 16 (exact, no remainder)

// ---------------------------------------------------------------- kernel 1 --
// Zero scan. flat = ((b*64+c)*256+w)*256+h, so (w*256+h) = flat & 65535.
// Thread idx handles float4 indices idx + k*STRIDE, k = 0..15. Bit (k*4+c)
// of the per-thread mask marks a zero at component c of iteration k.
__global__ __launch_bounds__(256) void count_zeros_kernel(
    const uint4v* __restrict__ a, const uint4v* __restrict__ b,
    unsigned int* __restrict__ za, unsigned int* __restrict__ zb) {
    int idx = blockIdx.x * BLOCK + threadIdx.x;
    unsigned long long ma = 0ull;
    unsigned long long mb = 0ull;
#pragma unroll 2
    for (int k = 0; k < ITERS; ++k) {
        uint4v va = __builtin_nontemporal_load(&a[idx + k * STRIDE]);
        uint4v vb = __builtin_nontemporal_load(&b[idx + k * STRIDE]);
        // (u<<1)==0 is true exactly for the bit patterns of +-0.0f
        unsigned long long ha = (((va.x << 1) == 0u) ? 1ull : 0ull)
                              | (((va.y << 1) == 0u) ? 2ull : 0ull)
                              | (((va.z << 1) == 0u) ? 4ull : 0ull)
                              | (((va.w << 1) == 0u) ? 8ull : 0ull);
        unsigned long long hb = (((vb.x << 1) == 0u) ? 1ull : 0ull)
                              | (((vb.y << 1) == 0u) ? 2ull : 0ull)
                              | (((vb.z << 1) == 0u) ? 4ull : 0ull)
                              | (((vb.w << 1) == 0u) ? 8ull : 0ull);
        ma |= ha << (k * 4);
        mb |= hb << (k * 4);
    }
    // cold epilogue: zeros are ~4 per tensor, so this runs on ~8 threads
    // in the entire grid. Atomics + loops here cannot hurt the hot loop.
    if (__builtin_expect(ma != 0ull, 0)) {
        while (ma) {
            int bit = __builtin_ctzll(ma);
            ma &= ma - 1;
            int k = bit >> 2, c = bit & 3;
            unsigned e = (((unsigned)(idx + k * STRIDE)) * 4u + (unsigned)c)
                         & (unsigned)(WH - 1);
            atomicAdd(&za[e], 1u);
        }
    }
    if (__builtin_expect(mb != 0ull, 0)) {
        while (mb) {
            int bit = __builtin_ctzll(mb);
            mb &= mb - 1;
            int k = bit >> 2, c = bit & 3;
            unsigned e = (((unsigned)(idx + k * STRIDE)) * 4u + (unsigned)c)
                         & (unsigned)(WH - 1);
            atomicAdd(&zb[e], 1u);
        }
    }
}

// ---------------------------------------------------------------- kernel 2 --
// One block per w (256 blocks), one thread per j (256 threads).
// Step 1: block-reduce the two row entropies e_fo[w], e_f5[w].
// Step 2: thread j loops i=0..255 computing the joint-entropy column sum,
//         then the smooth-L1 element; block-reduce -> partial[w].
__global__ void joint_loss_kernel(const unsigned int* __restrict__ za,
                                  const unsigned int* __restrict__ zb,
                                  float* __restrict__ partial) {
    __shared__ float redA[256];
    __shared__ float redB[256];
    int w = blockIdx.x;
    int t = threadIdx.x;

    // entropy terms: h = t
    float qa = (float)za[w * 256 + t] * (1.0f / 65536.0f);
    float qb = (float)zb[w * 256 + t] * (1.0f / 65536.0f);
    redA[t] = qa * logf(qa + 1e-8f);   // 0 when qa==0 (0 * finite)
    redB[t] = qb * logf(qb + 1e-8f);
    __syncthreads();
    for (int s = 128; s > 0; s >>= 1) {
        if (t < s) {
            redA[t] += redA[t + s];
            redB[t] += redB[t + s];
        }
        __syncthreads();
    }
    float ea = -redA[0];   // e_fo[w]
    float eb = -redB[0];   // e_f5[w]
    __syncthreads();

    // which bin does each row-entropy value match? (reference: x == i test)
    int ia = (ea == floorf(ea) && ea >= 0.0f && ea <= 255.0f) ? (int)ea : -1;
    int ib = (eb == floorf(eb) && eb >= 0.0f && eb <= 255.0f) ? (int)eb : -1;

    int j = t;
    float p0 = (j == ib) ? 1.0f : 0.0f;  // c=0 channel of x_p at bin j
    float sum_i = 0.0f;
    for (int i = 0; i < 256; ++i) {
        float m0   = (i == ia) ? 1.0f : 0.0f;             // c=0 of x_ms
        float base = ((i == 0) == (j == 0)) ? 255.0f : 0.0f;  // 255 c>=1 chans
        float c0   = m0 * p0 + (1.0f - m0) * (1.0f - p0);
        float s    = base + c0;
        float pm   = s * (1.0f / 65536.0f);
        sum_i += pm * logf(pm + 1e-8f);   // pm==0 -> exact 0 contribution
    }
    float J = -256.0f * sum_i;
    float S = (j == 0) ? (ea + eb) : 0.0f;
    float d = S - J;
    float ad = fabsf(d);
    float loss = (ad < 1.0f) ? 0.5f * d * d : ad - 0.5f;

    redA[t] = loss;
    __syncthreads();
    for (int s = 128; s > 0; s >>= 1) {
        if (t < s) redA[t] += redA[t + s];
        __syncthreads();
    }
    if (t == 0) partial[w] = redA[0];
}

// ---------------------------------------------------------------- kernel 3 --
__global__ void final_reduce_kernel(const float* __restrict__ partial,
                                    float* __restrict__ out) {
    __shared__ float red[256];
    int t = threadIdx.x;
    red[t] = partial[t];
    __syncthreads();
    for (int s = 128; s > 0; s >>= 1) {
        if (t < s) red[t] += red[t + s];
        __syncthreads();
    }
    if (t == 0) out[0] = red[0] * (1.0f / 65536.0f);
}

extern "C" void kernel_launch(void* const* d_in, const int* in_sizes, int n_in,
                              void* d_out, int out_size, void* d_ws, size_t ws_size,
                              hipStream_t stream) {
    const float* fo = (const float*)d_in[0];
    const float* f5 = (const float*)d_in[1];
    float* out = (float*)d_out;

    unsigned int* za = (unsigned int*)d_ws;
    unsigned int* zb = za + WH;
    float* partial   = (float*)(zb + WH);

    // zero the counters (ws is poisoned 0xAA before every launch)
    (void)hipMemsetAsync(d_ws, 0, 2 * WH * sizeof(unsigned int), stream);

    count_zeros_kernel<<<GRID, BLOCK, 0, stream>>>(
        (const uint4v*)fo, (const uint4v*)f5, za, zb);
    joint_loss_kernel<<<256, 256, 0, stream>>>(za, zb, partial);
    final_reduce_kernel<<<1, 256, 0, stream>>>(partial, out);
}